// Round 10
// baseline (253.315 us; speedup 1.0000x reference)
//
#include <hip/hip_runtime.h>
#include <hip/hip_bf16.h>
#include <math.h>

#define N_NODES 50000
#define E_EDGES 1600000
#define HF 128          // H*F = 4*32
#define INV_CUTOFF 0.25f
#define ENV_A -36.0f
#define ENV_B 63.0f
#define ENV_C -28.0f

#define GEMM_BLOCKS ((N_NODES + 63) / 64)   // 782: 64 rows per block (16/wave)
#define REC_CAP 72    // slots per node; deg ~ Poisson(32), 7.2 sigma tail
#define BNODES 64     // nodes per bucket (and per agg block)
#define NBUCK 782     // buckets of 64 nodes: bucket = dst >> 6
#define BUCK_CAP 2560 // mean 2048, sd ~45 -> 11 sigma
#define EPB 6250      // edges per bucketize block (256 blocks exact)

typedef __attribute__((ext_vector_type(8))) short bf16x8;
typedef __attribute__((ext_vector_type(4))) float f32x4;

// round-to-nearest-even fp32 -> bf16 bits
__device__ __forceinline__ unsigned short f2bf(float f) {
  unsigned u = __float_as_uint(f);
  u += 0x7fffu + ((u >> 16) & 1u);
  return (unsigned short)(u >> 16);
}
__device__ __forceinline__ unsigned pack2(float lo, float hi) {
  return (unsigned)f2bf(lo) | ((unsigned)f2bf(hi) << 16);
}
__device__ __forceinline__ float2 up2(unsigned v) {
  return make_float2(__uint_as_float(v << 16), __uint_as_float(v & 0xffff0000u));
}

// ---- plain float2 helpers (no inline asm; VOP3 fma gets free abs modifier) --
__device__ __forceinline__ float2 p2add(float2 a, float2 b) {
  return make_float2(a.x + b.x, a.y + b.y);
}
__device__ __forceinline__ float2 p2fma(float2 a, float2 b, float2 c) {
  return make_float2(fmaf(a.x, b.x, c.x), fmaf(a.y, b.y, c.y));
}
__device__ __forceinline__ float2 p2abs(float2 a) {
  return make_float2(fabsf(a.x), fabsf(a.y));
}
__device__ __forceinline__ float2 p2fmas(float s, float2 b, float2 c) {
  return make_float2(fmaf(s, b.x, c.x), fmaf(s, b.y, c.y));
}

// ---------------- Kernel 1: phase1 = feat GEMM blocks ∥ bucketize blocks -----
// blocks [0, GEMM_BLOCKS): MFMA feature GEMM (W converted+swizzled in staging).
// blocks [GEMM_BLOCKS, +256): bucketize into 64-node buckets.
__global__ __launch_bounds__(256) void phase1(
    const float* __restrict__ x, const float* __restrict__ Ws,
    const float* __restrict__ Wd,
    const float* __restrict__ bs, const float* __restrict__ bd,
    unsigned short* __restrict__ fs, float* __restrict__ fd,
    const int* __restrict__ dst, const int* __restrict__ src,
    const float* __restrict__ dist,
    int* __restrict__ bcursor, unsigned* __restrict__ bb_pay,
    unsigned char* __restrict__ bb_loc) {
  __shared__ __align__(16) char smem[65536];   // shared by both paths

  if (blockIdx.x < GEMM_BLOCKS) {
    // ================= GEMM path =================
    unsigned short* wlds = (unsigned short*)smem;   // 64 KB: W, then C-stage

    // stage W: 4096 16B chunks / 256 thr; convert fp32->bf16 + swizzle
    for (int i = threadIdx.x; i < 4096; i += 256) {
      const int n = i >> 4, c = i & 15;
      const float* Wp = ((n < 128) ? Ws : Wd) + (size_t)(n & 127) * HF + c * 8;
      const float4 v0 = *(const float4*)Wp;
      const float4 v1 = *(const float4*)(Wp + 4);
      uint4 pk;
      pk.x = pack2(v0.x, v0.y); pk.y = pack2(v0.z, v0.w);
      pk.z = pack2(v1.x, v1.y); pk.w = pack2(v1.z, v1.w);
      ((uint4*)wlds)[n * 16 + (c ^ (n & 15))] = pk;
    }

    const int lane = threadIdx.x & 63;
    const int wave = threadIdx.x >> 6;
    const int m = lane & 15;
    const int quad = lane >> 4;
    const int row = blockIdx.x * 64 + wave * 16 + m;
    const int rowc = (row < N_NODES) ? row : (N_NODES - 1);

    union { bf16x8 v; unsigned u[4]; } af[4];
    #pragma unroll
    for (int kt = 0; kt < 4; kt++) {
      const float* xp = x + (size_t)rowc * HF + kt * 32 + quad * 8;
      const float4 u0 = *(const float4*)xp;
      const float4 u1 = *(const float4*)(xp + 4);
      af[kt].u[0] = pack2(u0.x, u0.y); af[kt].u[1] = pack2(u0.z, u0.w);
      af[kt].u[2] = pack2(u1.x, u1.y); af[kt].u[3] = pack2(u1.z, u1.w);
    }

    __syncthreads();

    float accA[16][4];
    #pragma unroll
    for (int nt = 0; nt < 16; nt++) {
      const int nrow = nt * 16 + m;
      f32x4 acc = {0.f, 0.f, 0.f, 0.f};
      #pragma unroll
      for (int kt = 0; kt < 4; kt++) {
        const int pc = (kt * 4 + quad) ^ m;
        const bf16x8 bf = *(const bf16x8*)(wlds + (size_t)nrow * HF + pc * 8);
        acc = __builtin_amdgcn_mfma_f32_16x16x32_bf16(af[kt].v, bf, acc, 0, 0, 0);
      }
      accA[nt][0] = acc[0]; accA[nt][1] = acc[1];
      accA[nt][2] = acc[2]; accA[nt][3] = acc[3];
    }

    __syncthreads();   // reuse LDS as C-stage
    unsigned short* fsS = wlds;                       // bf16 [64][136]
    float* fdS = (float*)(wlds + 64 * 136);           // f32  [64][132]

    const int rl0 = wave * 16 + quad * 4;
    #pragma unroll
    for (int nt = 0; nt < 16; nt++) {
      const int col = nt * 16 + m;
      if (col < 128) {
        const float bias = bs[col];
        #pragma unroll
        for (int r = 0; r < 4; r++)
          fsS[(rl0 + r) * 136 + col] = f2bf(accA[nt][r] + bias);
      } else {
        const float bias = bd[col - 128];
        #pragma unroll
        for (int r = 0; r < 4; r++)
          fdS[(rl0 + r) * 132 + (col - 128)] = accA[nt][r] + bias;
      }
    }
    __syncthreads();

    for (int c = threadIdx.x; c < 1024; c += 256) {
      const int r = c >> 4, off = (c & 15) * 8;
      const int gr = blockIdx.x * 64 + r;
      if (gr < N_NODES)
        *(uint4*)(fs + (size_t)gr * HF + off) = *(const uint4*)(fsS + r * 136 + off);
    }
    for (int c = threadIdx.x; c < 2048; c += 256) {
      const int r = c >> 5, off = (c & 31) * 4;
      const int gr = blockIdx.x * 64 + r;
      if (gr < N_NODES)
        *(float4*)(fd + (size_t)gr * HF + off) = *(const float4*)(fdS + r * 132 + off);
    }
  } else {
    // ================= bucketize path (64-node buckets) =================
    unsigned* pay_s      = (unsigned*)smem;                     // 25000 B
    unsigned short* bkt_s = (unsigned short*)(smem + 25000);    // 12500 B
    unsigned char* loc_s = (unsigned char*)(smem + 37500);      // 6250 B
    int* hist = (int*)(smem + 43752);                           // 3128 B each
    int* loff = hist + NBUCK;
    int* base = loff + NBUCK;
    int* cur  = base + NBUCK;
    int* part = cur + NBUCK;                                    // 1024 B

    const int bb = blockIdx.x - GEMM_BLOCKS;   // 0..255
    for (int t = threadIdx.x; t < NBUCK; t += 256) { hist[t] = 0; cur[t] = 0; }
    __syncthreads();
    const int lo = bb * EPB;   // 256*6250 == E_EDGES exactly
    for (int k = threadIdx.x; k < EPB; k += 256)
      atomicAdd(&hist[dst[lo + k] >> 6], 1);
    __syncthreads();
    // parallel exclusive prefix over 782 buckets: 4-bucket chunks + scan
    int s = 0;
    const int b0 = threadIdx.x * 4;
    #pragma unroll
    for (int k = 0; k < 4; k++) {
      const int bi = b0 + k;
      if (bi < NBUCK) s += hist[bi];
    }
    part[threadIdx.x] = s;
    __syncthreads();
    for (int offm = 1; offm < 256; offm <<= 1) {
      const int v = (threadIdx.x >= offm) ? part[threadIdx.x - offm] : 0;
      __syncthreads();
      part[threadIdx.x] += v;
      __syncthreads();
    }
    int run = part[threadIdx.x] - s;   // exclusive prefix of this chunk
    #pragma unroll
    for (int k = 0; k < 4; k++) {
      const int bi = b0 + k;
      if (bi < NBUCK) { loff[bi] = run; run += hist[bi]; }
    }
    __syncthreads();
    for (int t = threadIdx.x; t < NBUCK; t += 256)
      base[t] = atomicAdd(&bcursor[t], hist[t]);
    __syncthreads();
    for (int k = threadIdx.x; k < EPB; k += 256) {
      const int d = dst[lo + k];
      const int b = d >> 6;
      float ds = dist[lo + k] * (INV_CUTOFF * 65536.f);
      unsigned dq = (unsigned)(ds + 0.5f);
      if (dq > 65535u) dq = 65535u;
      const int sdx = loff[b] + atomicAdd(&cur[b], 1);
      pay_s[sdx] = (unsigned)src[lo + k] | (dq << 16);
      bkt_s[sdx] = (unsigned short)b;
      loc_s[sdx] = (unsigned char)(d & 63);
    }
    __syncthreads();
    // flush: consecutive sdx within a bucket -> consecutive dest (coalesced)
    for (int sdx = threadIdx.x; sdx < EPB; sdx += 256) {
      const int b = bkt_s[sdx];
      const int dest = base[b] + (sdx - loff[b]);
      if (dest < BUCK_CAP) {
        bb_pay[(size_t)b * BUCK_CAP + dest] = pay_s[sdx];
        bb_loc[(size_t)b * BUCK_CAP + dest] = loc_s[sdx];
      }
    }
  }
}

// ---------------- Kernel 2: fused bucket scatter + per-node aggregation -----
// Block b owns nodes [b*64, b*64+64). Phase A: rank this bucket's edges into
// per-node LDS lists (recS). Phase B: 16 waves x 4 nodes run the proven agg
// body reading rec/counts from LDS (no global rec round-trip, no counts[]).
__global__ __launch_bounds__(1024) void bucket_agg(
    const unsigned short* __restrict__ fs, const float* __restrict__ fd,
    const int* __restrict__ bcursor, const unsigned* __restrict__ bb_pay,
    const unsigned char* __restrict__ bb_loc,
    const float* __restrict__ attn, const float* __restrict__ alpha_p,
    const float* __restrict__ freqs, float* __restrict__ out) {
  __shared__ int cnt[BNODES];
  __shared__ unsigned recS[BNODES * REC_CAP];   // 18432 B
  const int b = blockIdx.x;

  if (threadIdx.x < BNODES) cnt[threadIdx.x] = 0;
  __syncthreads();

  const int total = min(bcursor[b], BUCK_CAP);
  const size_t bbase = (size_t)b * BUCK_CAP;
  for (int i = threadIdx.x; i < total; i += 1024) {
    const unsigned pay = bb_pay[bbase + i];
    const int local = bb_loc[bbase + i];
    const int r = atomicAdd(&cnt[local], 1);
    if (r < REC_CAP) recS[local * REC_CAP + r] = pay;
  }
  __syncthreads();

  const int wave = threadIdx.x >> 6;
  const int lane = threadIdx.x & 63;
  const int eslot = lane >> 4;
  const int h = (lane >> 2) & 3;
  const int j = lane & 3;
  const int fo = (h << 5) + (j << 3);   // h*32 + j*8

  const float2 t0 = *(const float2*)(attn + fo + 0);
  const float2 t1 = *(const float2*)(attn + fo + 2);
  const float2 t2 = *(const float2*)(attn + fo + 4);
  const float2 t3 = *(const float2*)(attn + fo + 6);
  const float al = alpha_p[h];
  const float c1 = 0.5f * (1.0f + al);
  const float c2 = 0.5f * (1.0f - al);
  const float fr = freqs[h];
  const unsigned short* fsp = fs + fo;

  #pragma unroll 1
  for (int nn = 0; nn < 4; nn++) {
    const int local = wave * 4 + nn;
    const int node = b * BNODES + local;
    if (node >= N_NODES) break;

    int c = cnt[local];
    c = (c < REC_CAP) ? c : REC_CAP;
    const unsigned* recp = recS + local * REC_CAP;

    const float* fdp = fd + (size_t)node * HF + fo;
    const float2 f0 = *(const float2*)(fdp + 0);
    const float2 f1 = *(const float2*)(fdp + 2);
    const float2 f2 = *(const float2*)(fdp + 4);
    const float2 f3 = *(const float2*)(fdp + 6);

    float l = 0.f;
    float2 A0 = {0.f, 0.f}, A1 = {0.f, 0.f}, A2 = {0.f, 0.f}, A3 = {0.f, 0.f};

    for (int i = 0; i < c; i += 4) {
      const int idx = i + eslot;
      const bool valid = (idx < c);
      const unsigned r = recp[valid ? idx : 0];
      const int s_idx = (int)(r & 0xffffu);
      const float d = (float)(r >> 16) * (1.0f / 65536.0f);   // = dist/CUTOFF
      const uint4 eb = *(const uint4*)(fsp + ((size_t)s_idx << 7));  // 8 bf16
      const float2 e0 = up2(eb.x);
      const float2 e1 = up2(eb.y);
      const float2 e2 = up2(eb.z);
      const float2 e3 = up2(eb.w);

      // bessel coeff: env(d)*sin(freq*d); env = d + d^7*(A + B d + C d^2)
      const float d2 = d * d;
      const float d4 = d2 * d2;
      const float d7 = d4 * d2 * d;
      const float env = fmaf(d7, fmaf(d, fmaf(d, ENV_C, ENV_B), ENV_A), d);
      const float cf = env * __sinf(fr * d);
      const float k1 = c1 * cf;
      const float k2 = c2 * fabsf(cf);

      // D1 = sum(attn*u), D2 = sum(attn*|u|), u = el + fd
      float2 D1 = {0.f, 0.f}, D2 = {0.f, 0.f};
      float2 u;
      u = p2add(e0, f0); D1 = p2fma(u, t0, D1); D2 = p2fma(p2abs(u), t0, D2);
      u = p2add(e1, f1); D1 = p2fma(u, t1, D1); D2 = p2fma(p2abs(u), t1, D2);
      u = p2add(e2, f2); D1 = p2fma(u, t2, D1); D2 = p2fma(p2abs(u), t2, D2);
      u = p2add(e3, f3); D1 = p2fma(u, t3, D1); D2 = p2fma(p2abs(u), t3, D2);

      // p = k1*sum(D1) + k2*sum(D2), then reduce over the 4 j-lanes
      float p = fmaf(k1, D1.x + D1.y, k2 * (D2.x + D2.y));
      p += __shfl_xor(p, 1);
      p += __shfl_xor(p, 2);

      const float w = valid ? __expf(p) : 0.f;
      l += w;
      A0 = p2fmas(w, e0, A0);
      A1 = p2fmas(w, e1, A1);
      A2 = p2fmas(w, e2, A2);
      A3 = p2fmas(w, e3, A3);
    }

    // combine the 4 edge slots (lanes differing in bits 4,5)
    #pragma unroll
    for (int mm = 16; mm < 64; mm <<= 1) {
      l    += __shfl_xor(l, mm);
      A0.x += __shfl_xor(A0.x, mm); A0.y += __shfl_xor(A0.y, mm);
      A1.x += __shfl_xor(A1.x, mm); A1.y += __shfl_xor(A1.y, mm);
      A2.x += __shfl_xor(A2.x, mm); A2.y += __shfl_xor(A2.y, mm);
      A3.x += __shfl_xor(A3.x, mm); A3.y += __shfl_xor(A3.y, mm);
    }

    if (eslot == 0) {
      const float rl = (l > 0.f) ? 1.0f / l : 0.f;
      float* o = out + (size_t)node * HF + fo;
      float4 o0 = {A0.x * rl, A0.y * rl, A1.x * rl, A1.y * rl};
      float4 o1 = {A2.x * rl, A2.y * rl, A3.x * rl, A3.y * rl};
      *(float4*)o = o0;
      *(float4*)(o + 4) = o1;
    }
  }
}

// ---------------- launcher ----------------
extern "C" void kernel_launch(void* const* d_in, const int* in_sizes, int n_in,
                              void* d_out, int out_size, void* d_ws, size_t ws_size,
                              hipStream_t stream) {
  const float* x      = (const float*)d_in[0];
  const float* dist   = (const float*)d_in[1];
  const float* W_src  = (const float*)d_in[2];
  const float* b_src  = (const float*)d_in[3];
  const float* W_dst  = (const float*)d_in[4];
  const float* b_dst  = (const float*)d_in[5];
  const float* attn   = (const float*)d_in[6];
  const float* alpha  = (const float*)d_in[7];
  const float* freqs  = (const float*)d_in[8];
  const int*   src    = (const int*)d_in[9];
  const int*   dst    = (const int*)d_in[10];
  float* out = (float*)d_out;

  char* w = (char*)d_ws;
  size_t off = 0;
  auto alloc = [&](size_t bytes) -> void* {
    void* p = w + off;
    off += (bytes + 255) & ~(size_t)255;
    return p;
  };
  unsigned short* feat_src = (unsigned short*)alloc((size_t)N_NODES * HF * 2);
  float*          feat_dst = (float*)alloc((size_t)N_NODES * HF * 4);
  int*            bcursor  = (int*)alloc((size_t)NBUCK * 4);
  unsigned*       bb_pay   = (unsigned*)alloc((size_t)NBUCK * BUCK_CAP * 4);
  unsigned char*  bb_loc   = (unsigned char*)alloc((size_t)NBUCK * BUCK_CAP);

  hipMemsetAsync(bcursor, 0, (size_t)NBUCK * 4, stream);

  phase1<<<GEMM_BLOCKS + 256, 256, 0, stream>>>(
      x, W_src, W_dst, b_src, b_dst, feat_src, feat_dst,
      dst, src, dist, bcursor, bb_pay, bb_loc);

  bucket_agg<<<NBUCK, 1024, 0, stream>>>(
      feat_src, feat_dst, bcursor, bb_pay, bb_loc, attn, alpha, freqs, out);
}